// Round 4
// baseline (185.564 us; speedup 1.0000x reference)
//
#include <hip/hip_runtime.h>
#include <hip/hip_bf16.h>

// VectorQuantize: B=4, N=2048, DIM=256, HEADS=4, CODEBOOK=8192, HD=64
// Established (R0-R10): inputs fp32, output fp32 (quantize ++ indices-as-floats).
// R10: fp16 2-level split, 3 MFMA terms, 139.6us dist / 190 total.
// R11: zero-C init + epilogue ycn + setprio: dist 128, total 178.8 (tail 51).
// R12: fused merge w/ __threadfence: DISASTER (L2 writeback thrash, 296us).
// R13: fence-free fusion (packed 64b atomicMax publish + election winner):
//   dist ~137, total 176.2. Occupancy ~19.6% ~= 2 blocks/CU << 4 allowed by
//   LDS/VGPR(128 reported) => suspect real reg footprint > 128 (W1) vs
//   broken derived counter (W2).
// R14 (this round): register-footprint restructure, work held constant:
//   rt 4->2 (32 q/wave, 128 q/block), NPART 8->4 (CPART=2048, NSTAGE=32),
//   grid stays 1024. Per-block MACs & staging bytes UNCHANGED. A-frags halve
//   (64->32 VGPR). y2s[CPART] -> stage-local y2d[2][64] (512B; reads are
//   stage-local), LDS 36.9->33.3KB. Target: unambiguous 4 blocks/CU.
//   W1 pred: dist ~95-110us. W2 pred: ~140-150 (then R15 = epilogue VALU cut).

#define HEADS    4
#define CODEBOOK 8192
#define HD       64
#define BQ       8192                  // queries per head = B*N
#define QOFF     (4 * 2048 * 256)      // quantize FLOAT elements in d_out
#define NPART    4
#define CPART    (CODEBOOK / NPART)    // 2048 codes per partition
#define SCODES   64                    // codes per stage
#define NSTAGE   (CPART / SCODES)      // 32 stages
#define QBLOCK   128                   // queries per block (2 rt x 16 x 4 waves)
#define RSCALE   4096.0f               // residual scale (2^12)
#define RINV     (1.0f / 4096.0f)

typedef _Float16 f16x8 __attribute__((ext_vector_type(8)));
typedef float    f32x4 __attribute__((ext_vector_type(4)));

__device__ unsigned long long g_best[HEADS * BQ]; // packed (sortable score, ~idx)
__device__ int                g_cnt[HEADS * 64];  // per-(h,qg) arrival counter

// split fp32 -> 2 fp16 levels: f ~= (float)h0 + (float)h1 / 4096, |err|<=2^-24|f|
__device__ inline void split2(float f, _Float16& h0, _Float16& h1) {
    h0 = (_Float16)f;
    float r = f - (float)h0;
    h1 = (_Float16)(r * RSCALE);
}

// order-preserving float->uint32 (finite values; scores are finite)
__device__ inline unsigned sortable(float v) {
    unsigned s = __float_as_uint(v);
    return s ^ ((s & 0x80000000u) ? 0xFFFFFFFFu : 0x80000000u);
}

// ---------------- fused kernel: scores + argmax + election merge ----------
// grid = 1024 = head(4) x qgroup(64) x part(4); block = 256 (4 waves).
// Each wave owns 32 queries (2 pinned A row-tiles); block scans one 2048-code
// partition in 32 stages of 64 codes through double-buffered, XOR-swizzled LDS
// (conflict-free b128 write+read — verified R5/R8: SQ_LDS_BANK_CONFLICT == 0).
// y2 (= -0.5||e||^2) computed in the staging path, stage-local dbuf y2d[2][64].
// MFMA 16x16x32_f16 layouts (HW-verified family):
//   A: lane -> A[m=lane&15][k=quad*8+j];  B: lane -> B[k=quad*8+j][n=lane&15]
//   C: lane -> col=lane&15, row=quad*4+reg
__global__ __launch_bounds__(256, 2) void dist_kernel(const float* __restrict__ x,
                                                      const float* __restrict__ embed,
                                                      float* __restrict__ out) {
    __shared__ __align__(16) _Float16 tile[2][2][SCODES * 64];   // 32768 B
    __shared__ float y2d[2][SCODES];                             // 512 B
    __shared__ int s_old;

    const int bid  = blockIdx.x;
    const int part = bid & 3;
    const int qg   = (bid >> 2) & 63;
    const int h    = bid >> 8;
    const int t    = threadIdx.x;
    const int wave = t >> 6;
    const int lane = t & 63;
    const int col  = lane & 15;
    const int quad = lane >> 4;

    const int qbase = qg * QBLOCK + wave * 32;    // this wave's 32 queries
    const int cbase = part * CPART;

    // A fragments a[rowtile][level][khalf], split on the fly from fp32 x
    f16x8 a[2][2][2];
#pragma unroll
    for (int rt = 0; rt < 2; rt++) {
#pragma unroll
        for (int kh = 0; kh < 2; kh++) {
            const float* p = x + ((size_t)(qbase + rt * 16 + col) * 256 + h * 64 + kh * 32 + quad * 8);
#pragma unroll
            for (int j = 0; j < 8; j++) {
                _Float16 h0, h1;
                split2(p[j], h0, h1);
                a[rt][0][kh][j] = h0;
                a[rt][1][kh][j] = h1;
            }
        }
    }

    // staging: thread t owns rows (t>>3), (t>>3)+32, 8-float granule t&7
    const float* esrc = embed + ((size_t)h * CODEBOOK + cbase) * HD + (size_t)t * 8;
    const int row  = t >> 3;
    const int gsw  = (t & 7) ^ (row & 7);          // swizzled granule (same for row+32)
    const int ldA  = row * 64 + gsw * 8;           // f16 units within a level plane
    const int ldB  = (row + 32) * 64 + gsw * 8;

    float bv[2][4]; int bc[2][4];
#pragma unroll
    for (int rt = 0; rt < 2; rt++)
#pragma unroll
        for (int r = 0; r < 4; r++) { bv[rt][r] = -3.4e38f; bc[rt][r] = 0; }

    float4 pfA0, pfA1, pfB0, pfB1;                 // prefetch regs (2 rows x 8 floats)

    // split both rows -> 2 LDS planes of `buf`; also -0.5*y2 into y2d[buf]
    auto stage_write = [&](int buf) {
        float fA[8] = {pfA0.x, pfA0.y, pfA0.z, pfA0.w, pfA1.x, pfA1.y, pfA1.z, pfA1.w};
        float fB[8] = {pfB0.x, pfB0.y, pfB0.z, pfB0.w, pfB1.x, pfB1.y, pfB1.z, pfB1.w};
        f16x8 vA0, vA1, vB0, vB1;
        float ssA = 0.f, ssB = 0.f;
#pragma unroll
        for (int j = 0; j < 8; j++) {
            _Float16 h0, h1;
            split2(fA[j], h0, h1);
            vA0[j] = h0; vA1[j] = h1;
            ssA = fmaf(fA[j], fA[j], ssA);
            split2(fB[j], h0, h1);
            vB0[j] = h0; vB1[j] = h1;
            ssB = fmaf(fB[j], fB[j], ssB);
        }
        *reinterpret_cast<f16x8*>(&tile[buf][0][ldA]) = vA0;
        *reinterpret_cast<f16x8*>(&tile[buf][1][ldA]) = vA1;
        *reinterpret_cast<f16x8*>(&tile[buf][0][ldB]) = vB0;
        *reinterpret_cast<f16x8*>(&tile[buf][1][ldB]) = vB1;
#pragma unroll
        for (int off = 4; off >= 1; off >>= 1) {   // width-8 granule tree
            ssA += __shfl_xor(ssA, off, 8);
            ssB += __shfl_xor(ssB, off, 8);
        }
        if ((t & 7) == 0) {
            y2d[buf][row]      = -0.5f * ssA;
            y2d[buf][row + 32] = -0.5f * ssB;
        }
    };
    auto stage_load = [&](int stage) {
        const float* ps = esrc + (size_t)stage * (SCODES * HD);
        pfA0 = *reinterpret_cast<const float4*>(ps);
        pfA1 = *reinterpret_cast<const float4*>(ps + 4);
        pfB0 = *reinterpret_cast<const float4*>(ps + 32 * HD);
        pfB1 = *reinterpret_cast<const float4*>(ps + 32 * HD + 4);
    };

    // preamble: stage 0 staged + y2, stage 1 prefetched, publish
    stage_load(0);
    stage_write(0);
    stage_load(1);
    __syncthreads();

    const int swbase = col & 7;                    // read-side swizzle key
    const f32x4 z4 = {0.f, 0.f, 0.f, 0.f};        // persistent zero C-operand

    for (int s = 0; s < NSTAGE; s++) {
        // write stage s+1 (+ its y2) into the other buffer, then issue load of
        // stage s+2; the in-flight load drains at THIS stage's end barrier.
        if (s + 1 < NSTAGE) stage_write((s + 1) & 1);
        if (s + 2 < NSTAGE) stage_load(s + 2);

#pragma unroll
        for (int inner = 0; inner < 4; inner++) {
            const int rbase = (inner * 16 + col) * 64;     // row offset in plane
            f16x8 b[2][2];
#pragma unroll
            for (int lvl = 0; lvl < 2; lvl++)
#pragma unroll
                for (int kh = 0; kh < 2; kh++)
                    b[lvl][kh] = *reinterpret_cast<const f16x8*>(
                        &tile[s & 1][lvl][rbase + ((((kh << 2) | quad) ^ swbase) << 3)]);

            const int   cl  = inner * 16 + col;            // stage-local code
            const float ycn = y2d[s & 1][cl];              // -0.5*||e_c||^2
            const int   c   = s * SCODES + cl;             // partition-local code
#pragma unroll
            for (int rt = 0; rt < 2; rt++) {
                __builtin_amdgcn_s_setprio(1);
                f32x4 aA = __builtin_amdgcn_mfma_f32_16x16x32_f16(a[rt][0][0], b[0][0], z4, 0, 0, 0);
                f32x4 aB = __builtin_amdgcn_mfma_f32_16x16x32_f16(a[rt][0][0], b[1][0], z4, 0, 0, 0);
                aB = __builtin_amdgcn_mfma_f32_16x16x32_f16(a[rt][1][0], b[0][0], aB, 0, 0, 0);
                aA = __builtin_amdgcn_mfma_f32_16x16x32_f16(a[rt][0][1], b[0][1], aA, 0, 0, 0);
                aB = __builtin_amdgcn_mfma_f32_16x16x32_f16(a[rt][0][1], b[1][1], aB, 0, 0, 0);
                aB = __builtin_amdgcn_mfma_f32_16x16x32_f16(a[rt][1][1], b[0][1], aB, 0, 0, 0);
                __builtin_amdgcn_s_setprio(0);
#pragma unroll
                for (int r = 0; r < 4; r++) {
                    float sv = fmaf(aB[r], RINV, aA[r] + ycn); // xy - 0.5||e||^2
                    if (sv > bv[rt][r]) { bv[rt][r] = sv; bc[rt][r] = c; }
                }
            }
        }
        __syncthreads();
    }

    // reduce across 16 column slots; lexicographic (max val, min idx) =
    // np first-argmax tie-break; publish via packed device-scope atomicMax
#pragma unroll
    for (int rt = 0; rt < 2; rt++) {
#pragma unroll
        for (int r = 0; r < 4; r++) {
            float v = bv[rt][r]; int c = bc[rt][r];
#pragma unroll
            for (int off = 8; off >= 1; off >>= 1) {
                float ov = __shfl_xor(v, off, 16); int oc = __shfl_xor(c, off, 16);
                if (ov > v || (ov == v && oc < c)) { v = ov; c = oc; }
            }
            if (col == 0) {
                int q = h * BQ + qbase + rt * 16 + quad * 4 + r;
                unsigned long long pk =
                    ((unsigned long long)sortable(v) << 32) | (unsigned)(~(cbase + c));
                atomicMax(&g_best[q], pk);
            }
        }
    }

    // ---------------- election: last block of the (h,qg) group finalizes ---
    // __syncthreads drains vmcnt(0) => this block's atomicMaxes complete at
    // the coherent point before t0's counter add. No threadfence (R12 lesson).
    const int grp = (h << 6) | qg;
    __syncthreads();
    if (t == 0) s_old = atomicAdd(&g_cnt[grp], 1);
    __syncthreads();
    if (s_old != NPART - 1) return;  // not last -> done

    if (t == 0) atomicExch(&g_cnt[grp], 0);  // self-reset for next launch/replay

    // finalize 128 queries of (h,qg): coherent read via atomic RMW (add 0)
    int* sidx = reinterpret_cast<int*>(y2d);     // y2d dead; 128 ints = 512B fits
    const int m0 = qg * QBLOCK;
    if (t < QBLOCK) {
        const int q = h * BQ + m0 + t;
        unsigned long long pk = atomicAdd(&g_best[q], 0ull);
        int mc = (int)(~(unsigned)pk) & (CODEBOOK - 1);
        out[QOFF + (size_t)(m0 + t) * 4 + h] = (float)mc;   // embed_ind[b][n][h]
        sidx[t] = mc;
    }
    __syncthreads();

    // gather: wave owns 32 rows; 16 lanes per row x 4 rows per iter -> fully
    // coalesced 256B reads per codebook row and 256B stores per output row.
    const int rr = lane >> 4;                    // row-in-quad 0..3
    const int fo = (lane & 15) * 4;              // float offset within head seg
#pragma unroll
    for (int i = 0; i < 8; i++) {
        const int r   = wave * 32 + i * 4 + rr;
        const int idx = sidx[r];
        const float4 v = *reinterpret_cast<const float4*>(
            embed + ((size_t)h * CODEBOOK + idx) * HD + fo);
        *reinterpret_cast<float4*>(out + (size_t)(m0 + r) * 256 + h * 64 + fo) = v;
    }
}

extern "C" void kernel_launch(void* const* d_in, const int* in_sizes, int n_in,
                              void* d_out, int out_size, void* d_ws, size_t ws_size,
                              hipStream_t stream) {
    const float* x     = (const float*)d_in[0];
    const float* embed = (const float*)d_in[1];
    float*       out   = (float*)d_out;

    dist_kernel<<<1024, 256, 0, stream>>>(x, embed, out);
}

// Round 5
// 180.675 us; speedup vs baseline: 1.0271x; 1.0271x over previous
//
#include <hip/hip_runtime.h>
#include <hip/hip_bf16.h>

// VectorQuantize: B=4, N=2048, DIM=256, HEADS=4, CODEBOOK=8192, HD=64
// Established (R0-R10): inputs fp32, output fp32 (quantize ++ indices-as-floats).
// R10: fp16 2-level split, 3 MFMA terms, 139.6us dist / 190 total.
// R11: zero-C init + epilogue ycn + setprio: dist 128, total 178.8 (tail 51).
// R12: fused merge w/ __threadfence: DISASTER (L2 writeback thrash, 296us).
// R13: fence-free fusion (packed 64b atomicMax + election winner):
//   dist ~137, total 176.2, NPART=8/16 stages.
// R14: rt=2/NPART=4/32 stages (regs 128->96): occupancy counter DID NOT MOVE
//   (19.6% both) => derived counter bogus (W2). 2x barriers cost +8us =>
//   ~0.5us per stage boundary => vmcnt(0) drain at __syncthreads is the
//   structural stall (prefetch forced to complete at every barrier).
// R15 (this round): R13 geometry + T4 counted-wait barriers at the 17 stage
//   boundaries: asm lgkmcnt(0) + raw s_barrier + memory-clobber fences both
//   sides. vmcnt NOT drained -> prefetch stays in flight across barriers
//   (compiler inserts counted vmcnt at the pf-register use). Election /
//   finalize keep plain __syncthreads (vmcnt drain there is load-bearing
//   for atomic ordering). y2d stage-local dbuf (LDS 33.3KB); sidx parks in
//   dead tile memory.

#define HEADS    4
#define CODEBOOK 8192
#define HD       64
#define BQ       8192                  // queries per head = B*N
#define QOFF     (4 * 2048 * 256)      // quantize FLOAT elements in d_out
#define NPART    8
#define CPART    (CODEBOOK / NPART)    // 1024 codes per partition
#define SCODES   64                    // codes per stage
#define NSTAGE   (CPART / SCODES)      // 16 stages
#define RSCALE   4096.0f               // residual scale (2^12)
#define RINV     (1.0f / 4096.0f)

typedef _Float16 f16x8 __attribute__((ext_vector_type(8)));
typedef float    f32x4 __attribute__((ext_vector_type(4)));

__device__ unsigned long long g_best[HEADS * BQ]; // packed (sortable score, ~idx)
__device__ int                g_cnt[HEADS * 32];  // per-(h,qg) arrival counter

// split fp32 -> 2 fp16 levels: f ~= (float)h0 + (float)h1 / 4096, |err|<=2^-24|f|
__device__ inline void split2(float f, _Float16& h0, _Float16& h1) {
    h0 = (_Float16)f;
    float r = f - (float)h0;
    h1 = (_Float16)(r * RSCALE);
}

// order-preserving float->uint32 (finite values; scores are finite)
__device__ inline unsigned sortable(float v) {
    unsigned s = __float_as_uint(v);
    return s ^ ((s & 0x80000000u) ? 0xFFFFFFFFu : 0x80000000u);
}

// Stage barrier: LDS visibility only (lgkmcnt), vmcnt deliberately NOT
// drained so global prefetch stays in flight across the barrier (T4).
// asm memory clobbers = compiler-level fences preventing LDS ops from
// migrating across the raw s_barrier (m194-199 verified plain-HIP pattern).
__device__ inline void stage_barrier() {
    asm volatile("s_waitcnt lgkmcnt(0)" ::: "memory");
    __builtin_amdgcn_s_barrier();
    asm volatile("" ::: "memory");
}

// ---------------- fused kernel: scores + argmax + election merge ----------
// grid = 1024 = head(4) x qgroup(32) x part(8); block = 256 (4 waves).
// Each wave owns 64 queries (4 pinned A row-tiles); block scans one 1024-code
// partition in 16 stages of 64 codes through double-buffered, XOR-swizzled LDS
// (conflict-free b128 write+read — verified R5/R8: SQ_LDS_BANK_CONFLICT == 0).
// y2 (= -0.5||e||^2) computed in the staging path, stage-local dbuf y2d[2][64].
// MFMA 16x16x32_f16 layouts (HW-verified family):
//   A: lane -> A[m=lane&15][k=quad*8+j];  B: lane -> B[k=quad*8+j][n=lane&15]
//   C: lane -> col=lane&15, row=quad*4+reg
__global__ __launch_bounds__(256, 2) void dist_kernel(const float* __restrict__ x,
                                                      const float* __restrict__ embed,
                                                      float* __restrict__ out) {
    __shared__ __align__(16) _Float16 tile[2][2][SCODES * 64];   // 32768 B
    __shared__ float y2d[2][SCODES];                             // 512 B
    __shared__ int s_old;

    const int bid  = blockIdx.x;
    const int part = bid & 7;
    const int qg   = (bid >> 3) & 31;
    const int h    = bid >> 8;
    const int t    = threadIdx.x;
    const int wave = t >> 6;
    const int lane = t & 63;
    const int col  = lane & 15;
    const int quad = lane >> 4;

    const int qbase = qg * 256 + wave * 64;       // this wave's 64 queries
    const int cbase = part * CPART;

    // A fragments a[rowtile][level][khalf], split on the fly from fp32 x
    f16x8 a[4][2][2];
#pragma unroll
    for (int rt = 0; rt < 4; rt++) {
#pragma unroll
        for (int kh = 0; kh < 2; kh++) {
            const float* p = x + ((size_t)(qbase + rt * 16 + col) * 256 + h * 64 + kh * 32 + quad * 8);
#pragma unroll
            for (int j = 0; j < 8; j++) {
                _Float16 h0, h1;
                split2(p[j], h0, h1);
                a[rt][0][kh][j] = h0;
                a[rt][1][kh][j] = h1;
            }
        }
    }

    // staging: thread t owns rows (t>>3), (t>>3)+32, 8-float granule t&7
    const float* esrc = embed + ((size_t)h * CODEBOOK + cbase) * HD + (size_t)t * 8;
    const int row  = t >> 3;
    const int gsw  = (t & 7) ^ (row & 7);          // swizzled granule (same for row+32)
    const int ldA  = row * 64 + gsw * 8;           // f16 units within a level plane
    const int ldB  = (row + 32) * 64 + gsw * 8;

    float bv[4][4]; int bc[4][4];
#pragma unroll
    for (int rt = 0; rt < 4; rt++)
#pragma unroll
        for (int r = 0; r < 4; r++) { bv[rt][r] = -3.4e38f; bc[rt][r] = 0; }

    float4 pfA0, pfA1, pfB0, pfB1;                 // prefetch regs (2 rows x 8 floats)

    // split both rows -> 2 LDS planes of `buf`; also -0.5*y2 into y2d[buf]
    auto stage_write = [&](int buf) {
        float fA[8] = {pfA0.x, pfA0.y, pfA0.z, pfA0.w, pfA1.x, pfA1.y, pfA1.z, pfA1.w};
        float fB[8] = {pfB0.x, pfB0.y, pfB0.z, pfB0.w, pfB1.x, pfB1.y, pfB1.z, pfB1.w};
        f16x8 vA0, vA1, vB0, vB1;
        float ssA = 0.f, ssB = 0.f;
#pragma unroll
        for (int j = 0; j < 8; j++) {
            _Float16 h0, h1;
            split2(fA[j], h0, h1);
            vA0[j] = h0; vA1[j] = h1;
            ssA = fmaf(fA[j], fA[j], ssA);
            split2(fB[j], h0, h1);
            vB0[j] = h0; vB1[j] = h1;
            ssB = fmaf(fB[j], fB[j], ssB);
        }
        *reinterpret_cast<f16x8*>(&tile[buf][0][ldA]) = vA0;
        *reinterpret_cast<f16x8*>(&tile[buf][1][ldA]) = vA1;
        *reinterpret_cast<f16x8*>(&tile[buf][0][ldB]) = vB0;
        *reinterpret_cast<f16x8*>(&tile[buf][1][ldB]) = vB1;
#pragma unroll
        for (int off = 4; off >= 1; off >>= 1) {   // width-8 granule tree
            ssA += __shfl_xor(ssA, off, 8);
            ssB += __shfl_xor(ssB, off, 8);
        }
        if ((t & 7) == 0) {
            y2d[buf][row]      = -0.5f * ssA;
            y2d[buf][row + 32] = -0.5f * ssB;
        }
    };
    auto stage_load = [&](int stage) {
        const float* ps = esrc + (size_t)stage * (SCODES * HD);
        pfA0 = *reinterpret_cast<const float4*>(ps);
        pfA1 = *reinterpret_cast<const float4*>(ps + 4);
        pfB0 = *reinterpret_cast<const float4*>(ps + 32 * HD);
        pfB1 = *reinterpret_cast<const float4*>(ps + 32 * HD + 4);
    };

    // preamble: stage 0 staged + y2, stage 1 prefetched, publish
    stage_load(0);
    stage_write(0);
    stage_load(1);
    stage_barrier();

    const int swbase = col & 7;                    // read-side swizzle key
    const f32x4 z4 = {0.f, 0.f, 0.f, 0.f};        // persistent zero C-operand

    for (int s = 0; s < NSTAGE; s++) {
        // write stage s+1 (+ its y2) into the other buffer, then issue load of
        // stage s+2; load stays in flight ACROSS the stage barrier (T4) and is
        // consumed by stage_write next stage (compiler inserts counted vmcnt).
        if (s + 1 < NSTAGE) stage_write((s + 1) & 1);
        if (s + 2 < NSTAGE) stage_load(s + 2);

#pragma unroll
        for (int inner = 0; inner < 4; inner++) {
            const int rbase = (inner * 16 + col) * 64;     // row offset in plane
            f16x8 b[2][2];
#pragma unroll
            for (int lvl = 0; lvl < 2; lvl++)
#pragma unroll
                for (int kh = 0; kh < 2; kh++)
                    b[lvl][kh] = *reinterpret_cast<const f16x8*>(
                        &tile[s & 1][lvl][rbase + ((((kh << 2) | quad) ^ swbase) << 3)]);

            const int   cl  = inner * 16 + col;            // stage-local code
            const float ycn = y2d[s & 1][cl];              // -0.5*||e_c||^2
            const int   c   = s * SCODES + cl;             // partition-local code
#pragma unroll
            for (int rt = 0; rt < 4; rt++) {
                __builtin_amdgcn_s_setprio(1);
                f32x4 aA = __builtin_amdgcn_mfma_f32_16x16x32_f16(a[rt][0][0], b[0][0], z4, 0, 0, 0);
                f32x4 aB = __builtin_amdgcn_mfma_f32_16x16x32_f16(a[rt][0][0], b[1][0], z4, 0, 0, 0);
                aB = __builtin_amdgcn_mfma_f32_16x16x32_f16(a[rt][1][0], b[0][0], aB, 0, 0, 0);
                aA = __builtin_amdgcn_mfma_f32_16x16x32_f16(a[rt][0][1], b[0][1], aA, 0, 0, 0);
                aB = __builtin_amdgcn_mfma_f32_16x16x32_f16(a[rt][0][1], b[1][1], aB, 0, 0, 0);
                aB = __builtin_amdgcn_mfma_f32_16x16x32_f16(a[rt][1][1], b[0][1], aB, 0, 0, 0);
                __builtin_amdgcn_s_setprio(0);
#pragma unroll
                for (int r = 0; r < 4; r++) {
                    float sv = fmaf(aB[r], RINV, aA[r] + ycn); // xy - 0.5||e||^2
                    if (sv > bv[rt][r]) { bv[rt][r] = sv; bc[rt][r] = c; }
                }
            }
        }
        stage_barrier();
    }

    // reduce across 16 column slots; lexicographic (max val, min idx) =
    // np first-argmax tie-break; publish via packed device-scope atomicMax
#pragma unroll
    for (int rt = 0; rt < 4; rt++) {
#pragma unroll
        for (int r = 0; r < 4; r++) {
            float v = bv[rt][r]; int c = bc[rt][r];
#pragma unroll
            for (int off = 8; off >= 1; off >>= 1) {
                float ov = __shfl_xor(v, off, 16); int oc = __shfl_xor(c, off, 16);
                if (ov > v || (ov == v && oc < c)) { v = ov; c = oc; }
            }
            if (col == 0) {
                int q = h * BQ + qbase + rt * 16 + quad * 4 + r;
                unsigned long long pk =
                    ((unsigned long long)sortable(v) << 32) | (unsigned)(~(cbase + c));
                atomicMax(&g_best[q], pk);
            }
        }
    }

    // ---------------- election: last block of the (h,qg) group finalizes ---
    // Plain __syncthreads here ON PURPOSE: its vmcnt(0)+lgkmcnt(0) drain is
    // load-bearing (all atomicMaxes at the coherent point before t0's add).
    const int grp = (h << 5) | qg;
    __syncthreads();
    if (t == 0) s_old = atomicAdd(&g_cnt[grp], 1);
    __syncthreads();
    if (s_old != NPART - 1) return;  // not last -> done

    if (t == 0) atomicExch(&g_cnt[grp], 0);  // self-reset for next launch/replay

    // finalize 256 queries of (h,qg): coherent read via atomic RMW (add 0)
    int* sidx = reinterpret_cast<int*>(tile);    // tile dead; park 256 idx
    const int m0 = qg * 256;
    {
        const int q = h * BQ + m0 + t;
        unsigned long long pk = atomicAdd(&g_best[q], 0ull);
        int mc = (int)(~(unsigned)pk) & (CODEBOOK - 1);
        out[QOFF + (size_t)(m0 + t) * 4 + h] = (float)mc;   // embed_ind[b][n][h]
        sidx[t] = mc;
    }
    __syncthreads();

    // gather: wave owns 64 rows; 16 lanes per row x 4 rows per iter -> fully
    // coalesced 256B reads per codebook row and 256B stores per output row.
    const int rr = lane >> 4;                    // row-in-quad 0..3
    const int fo = (lane & 15) * 4;              // float offset within head seg
#pragma unroll
    for (int i = 0; i < 16; i++) {
        const int r   = wave * 64 + i * 4 + rr;
        const int idx = sidx[r];
        const float4 v = *reinterpret_cast<const float4*>(
            embed + ((size_t)h * CODEBOOK + idx) * HD + fo);
        *reinterpret_cast<float4*>(out + (size_t)(m0 + r) * 256 + h * 64 + fo) = v;
    }
}

extern "C" void kernel_launch(void* const* d_in, const int* in_sizes, int n_in,
                              void* d_out, int out_size, void* d_ws, size_t ws_size,
                              hipStream_t stream) {
    const float* x     = (const float*)d_in[0];
    const float* embed = (const float*)d_in[1];
    float*       out   = (float*)d_out;

    dist_kernel<<<1024, 256, 0, stream>>>(x, embed, out);
}

// Round 6
// 176.039 us; speedup vs baseline: 1.0541x; 1.0263x over previous
//
#include <hip/hip_runtime.h>

// VectorQuantize: B=4, N=2048, DIM=256, HEADS=4, CODEBOOK=8192, HD=64
// Established (R0-R10): inputs fp32, output fp32 (quantize ++ indices-as-floats).
// R10: fp16 2-level split, 3 MFMA terms, 139.6us dist / 190 total.
// R11: zero-C init + epilogue ycn + setprio: dist 128, total 178.8 (tail 51).
// R12: fused merge w/ __threadfence: DISASTER (L2 writeback thrash).
// R13: fence-free fusion (packed 64b atomicMax + election): dist 137, tot 176.
// R14: reg restructure: occupancy counter frozen (bogus); 2x stages cost +8us
//   => ~1200 cyc marginal per stage_write+barrier.
// R15: counted-wait stage barriers: NEUTRAL (139) => vmcnt-drain theory dead.
//   Surviving theory: stage_write's serial chains (16x split2 cvt chains +
//   3-level shfl_xor tree + packing + ds_writes) are the per-stage cost.
// R16 (this round): pre-split planes + global_load_lds staging.
//   prep_kernel (once): embed -> g_e0/g_e1 f16 planes + g_y2 (-0.5||e||^2).
//   dist: stage via global_load_lds(16B) with PRE-SWIZZLED source addresses
//   (lane granule (l&7)^(l>>3), lane-only, stage-invariant) -> LDS layout
//   byte-identical to R13's verified conflict-free tile. stage_write GONE:
//   no split VALU, no shfl tree, no ds_writes in the loop. ycn read direct
//   from g_y2 (L1-hot). Plain __syncthreads (vmcnt drain now load-bearing
//   for gl_lds, and cheap: loads get a full inner-loop in flight).

#define HEADS    4
#define CODEBOOK 8192
#define HD       64
#define BQ       8192                  // queries per head = B*N
#define QOFF     (4 * 2048 * 256)      // quantize FLOAT elements in d_out
#define NPART    8
#define CPART    (CODEBOOK / NPART)    // 1024 codes per partition
#define SCODES   64                    // codes per stage
#define NSTAGE   (CPART / SCODES)      // 16 stages
#define RSCALE   4096.0f               // residual scale (2^12)
#define RINV     (1.0f / 4096.0f)

typedef _Float16 f16x8 __attribute__((ext_vector_type(8)));
typedef float    f32x4 __attribute__((ext_vector_type(4)));

__device__ _Float16 g_e0[HEADS * CODEBOOK * HD];  // 4 MB: fp16 level-0 plane
__device__ _Float16 g_e1[HEADS * CODEBOOK * HD];  // 4 MB: fp16 level-1 plane
__device__ float    g_y2[HEADS * CODEBOOK];       // -0.5*||e||^2
__device__ unsigned long long g_best[HEADS * BQ]; // packed (sortable score, ~idx)
__device__ int                g_cnt[HEADS * 32];  // per-(h,qg) arrival counter

// split fp32 -> 2 fp16 levels: f ~= (float)h0 + (float)h1 / 4096, |err|<=2^-24|f|
__device__ inline void split2(float f, _Float16& h0, _Float16& h1) {
    h0 = (_Float16)f;
    float r = f - (float)h0;
    h1 = (_Float16)(r * RSCALE);
}

// order-preserving float->uint32 (finite values; scores are finite)
__device__ inline unsigned sortable(float v) {
    unsigned s = __float_as_uint(v);
    return s ^ ((s & 0x80000000u) ? 0xFFFFFFFFu : 0x80000000u);
}

__device__ inline void gl_lds16(const void* g, void* l) {
    __builtin_amdgcn_global_load_lds(
        (const __attribute__((address_space(1))) void*)g,
        (__attribute__((address_space(3))) void*)l, 16, 0, 0);
}

// ---------------- kernel 0: pre-split embed into global planes ------------
// 1024 blocks x 256 thr; 8 threads per code row (granule t&7), 32 rows/block.
// Coalesced: wave reads 2KB contiguous, writes 1KB contiguous per plane.
__global__ __launch_bounds__(256) void prep_kernel(const float* __restrict__ embed) {
    const int t   = threadIdx.x;
    const int row = blockIdx.x * 32 + (t >> 3);    // h*CODEBOOK + c
    const int g   = t & 7;
    const float* p = embed + (size_t)row * HD + g * 8;
    float f[8];
    *reinterpret_cast<float4*>(&f[0]) = *reinterpret_cast<const float4*>(p);
    *reinterpret_cast<float4*>(&f[4]) = *reinterpret_cast<const float4*>(p + 4);
    f16x8 v0, v1;
    float ss = 0.f;
#pragma unroll
    for (int j = 0; j < 8; j++) {
        _Float16 h0, h1;
        split2(f[j], h0, h1);
        v0[j] = h0; v1[j] = h1;
        ss = fmaf(f[j], f[j], ss);
    }
    *reinterpret_cast<f16x8*>(&g_e0[(size_t)row * HD + g * 8]) = v0;
    *reinterpret_cast<f16x8*>(&g_e1[(size_t)row * HD + g * 8]) = v1;
#pragma unroll
    for (int off = 4; off >= 1; off >>= 1)
        ss += __shfl_xor(ss, off, 8);
    if (g == 0) g_y2[row] = -0.5f * ss;
}

// ---------------- kernel 1: fused scores + argmax + election merge --------
// grid = 1024 = head(4) x qgroup(32) x part(8); block = 256 (4 waves).
// Each wave owns 64 queries (4 pinned A row-tiles); block scans one 1024-code
// partition in 16 stages of 64 codes. Staging = 16 global_load_lds (16B) per
// stage per block (4/wave: wave w covers plane w&1, rows (w>>1)*32..+31),
// source pre-swizzled so LDS layout == R13's verified conflict-free tile:
// LDS slot g of row rr holds global granule g^(rr&7).
// MFMA 16x16x32_f16 layouts (HW-verified family):
//   A: lane -> A[m=lane&15][k=quad*8+j];  B: lane -> B[k=quad*8+j][n=lane&15]
//   C: lane -> col=lane&15, row=quad*4+reg
__global__ __launch_bounds__(256, 2) void dist_kernel(const float* __restrict__ x,
                                                      const float* __restrict__ embed,
                                                      float* __restrict__ out) {
    __shared__ __align__(16) _Float16 tile[2][2][SCODES * HD];   // 32768 B
    __shared__ int s_old;

    const int bid  = blockIdx.x;
    const int part = bid & 7;
    const int qg   = (bid >> 3) & 31;
    const int h    = bid >> 8;
    const int t    = threadIdx.x;
    const int wave = t >> 6;
    const int lane = t & 63;
    const int col  = lane & 15;
    const int quad = lane >> 4;

    const int qbase = qg * 256 + wave * 64;       // this wave's 64 queries
    const int cbase = part * CPART;

    // staging geometry: wave covers plane (wave&1), rows (wave>>1)*32..+31.
    // lane l: row-in-chunk l>>3, LDS slot l&7 (HW lane-linear), source
    // granule (l&7)^(l>>3)  [row&7 == l>>3 since all bases are %8==0].
    const int p  = wave & 1;
    const int hh = wave >> 1;
    const _Float16* eb   = p ? g_e1 : g_e0;
    const _Float16* gsrc = eb
        + ((size_t)(h * CODEBOOK + cbase + hh * 32 + (lane >> 3))) * HD
        + ((lane & 7) ^ (lane >> 3)) * 8;
    auto stage_issue = [&](int st, int buf) {
        const _Float16* src = gsrc + (size_t)st * (SCODES * HD);
#pragma unroll
        for (int i = 0; i < 4; i++)
            gl_lds16(src + i * 8 * HD, &tile[buf][p][(hh * 32 + i * 8) * HD]);
    };
    const float* y2p = g_y2 + h * CODEBOOK + cbase;

    // issue stage 0 staging first (overlaps the A-frag build's loads)
    stage_issue(0, 0);

    // A fragments a[rowtile][level][khalf], split on the fly from fp32 x
    f16x8 a[4][2][2];
#pragma unroll
    for (int rt = 0; rt < 4; rt++) {
#pragma unroll
        for (int kh = 0; kh < 2; kh++) {
            const float* xp = x + ((size_t)(qbase + rt * 16 + col) * 256 + h * 64 + kh * 32 + quad * 8);
#pragma unroll
            for (int j = 0; j < 8; j++) {
                _Float16 h0, h1;
                split2(xp[j], h0, h1);
                a[rt][0][kh][j] = h0;
                a[rt][1][kh][j] = h1;
            }
        }
    }

    float bv[4][4]; int bc[4][4];
#pragma unroll
    for (int rt = 0; rt < 4; rt++)
#pragma unroll
        for (int r = 0; r < 4; r++) { bv[rt][r] = -3.4e38f; bc[rt][r] = 0; }

    __syncthreads();                               // stage 0 landed

    const int swbase = col & 7;                    // read-side swizzle key
    const f32x4 z4 = {0.f, 0.f, 0.f, 0.f};        // persistent zero C-operand

    for (int s = 0; s < NSTAGE; s++) {
        // issue next stage's DMA into the other buffer; it has the whole
        // inner loop to land; __syncthreads' vmcnt(0) drain completes it.
        if (s + 1 < NSTAGE) stage_issue(s + 1, (s + 1) & 1);

#pragma unroll
        for (int inner = 0; inner < 4; inner++) {
            const int rbase = (inner * 16 + col) * HD;     // row offset in plane
            f16x8 b[2][2];
#pragma unroll
            for (int lvl = 0; lvl < 2; lvl++)
#pragma unroll
                for (int kh = 0; kh < 2; kh++)
                    b[lvl][kh] = *reinterpret_cast<const f16x8*>(
                        &tile[s & 1][lvl][rbase + ((((kh << 2) | quad) ^ swbase) << 3)]);

            const int   cl  = inner * 16 + col;            // stage-local code
            const int   c   = s * SCODES + cl;             // partition-local code
            const float ycn = y2p[c];                      // -0.5*||e_c||^2 (L1-hot)
#pragma unroll
            for (int rt = 0; rt < 4; rt++) {
                __builtin_amdgcn_s_setprio(1);
                f32x4 aA = __builtin_amdgcn_mfma_f32_16x16x32_f16(a[rt][0][0], b[0][0], z4, 0, 0, 0);
                f32x4 aB = __builtin_amdgcn_mfma_f32_16x16x32_f16(a[rt][0][0], b[1][0], z4, 0, 0, 0);
                aB = __builtin_amdgcn_mfma_f32_16x16x32_f16(a[rt][1][0], b[0][0], aB, 0, 0, 0);
                aA = __builtin_amdgcn_mfma_f32_16x16x32_f16(a[rt][0][1], b[0][1], aA, 0, 0, 0);
                aB = __builtin_amdgcn_mfma_f32_16x16x32_f16(a[rt][0][1], b[1][1], aB, 0, 0, 0);
                aB = __builtin_amdgcn_mfma_f32_16x16x32_f16(a[rt][1][1], b[0][1], aB, 0, 0, 0);
                __builtin_amdgcn_s_setprio(0);
#pragma unroll
                for (int r = 0; r < 4; r++) {
                    float sv = fmaf(aB[r], RINV, aA[r] + ycn); // xy - 0.5||e||^2
                    if (sv > bv[rt][r]) { bv[rt][r] = sv; bc[rt][r] = c; }
                }
            }
        }
        __syncthreads();
    }

    // reduce across 16 column slots; lexicographic (max val, min idx) =
    // np first-argmax tie-break; publish via packed device-scope atomicMax
#pragma unroll
    for (int rt = 0; rt < 4; rt++) {
#pragma unroll
        for (int r = 0; r < 4; r++) {
            float v = bv[rt][r]; int c = bc[rt][r];
#pragma unroll
            for (int off = 8; off >= 1; off >>= 1) {
                float ov = __shfl_xor(v, off, 16); int oc = __shfl_xor(c, off, 16);
                if (ov > v || (ov == v && oc < c)) { v = ov; c = oc; }
            }
            if (col == 0) {
                int q = h * BQ + qbase + rt * 16 + quad * 4 + r;
                unsigned long long pk =
                    ((unsigned long long)sortable(v) << 32) | (unsigned)(~(cbase + c));
                atomicMax(&g_best[q], pk);
            }
        }
    }

    // ---------------- election: last block of the (h,qg) group finalizes ---
    // Plain __syncthreads: its vmcnt(0)+lgkmcnt(0) drain is load-bearing
    // (all atomicMaxes at the coherent point before t0's add). R12 lesson:
    // no __threadfence.
    const int grp = (h << 5) | qg;
    __syncthreads();
    if (t == 0) s_old = atomicAdd(&g_cnt[grp], 1);
    __syncthreads();
    if (s_old != NPART - 1) return;  // not last -> done

    if (t == 0) atomicExch(&g_cnt[grp], 0);  // self-reset for next launch/replay

    // finalize 256 queries of (h,qg): coherent read via atomic RMW (add 0)
    int* sidx = reinterpret_cast<int*>(tile);    // tile dead; park 256 idx
    const int m0 = qg * 256;
    {
        const int q = h * BQ + m0 + t;
        unsigned long long pk = atomicAdd(&g_best[q], 0ull);
        int mc = (int)(~(unsigned)pk) & (CODEBOOK - 1);
        out[QOFF + (size_t)(m0 + t) * 4 + h] = (float)mc;   // embed_ind[b][n][h]
        sidx[t] = mc;
    }
    __syncthreads();

    // gather: wave owns 64 rows; 16 lanes per row x 4 rows per iter -> fully
    // coalesced 256B reads per codebook row and 256B stores per output row.
    const int rr = lane >> 4;                    // row-in-quad 0..3
    const int fo = (lane & 15) * 4;              // float offset within head seg
#pragma unroll
    for (int i = 0; i < 16; i++) {
        const int r   = wave * 64 + i * 4 + rr;
        const int idx = sidx[r];
        const float4 v = *reinterpret_cast<const float4*>(
            embed + ((size_t)h * CODEBOOK + idx) * HD + fo);
        *reinterpret_cast<float4*>(out + (size_t)(m0 + r) * 256 + h * 64 + fo) = v;
    }
}

extern "C" void kernel_launch(void* const* d_in, const int* in_sizes, int n_in,
                              void* d_out, int out_size, void* d_ws, size_t ws_size,
                              hipStream_t stream) {
    const float* x     = (const float*)d_in[0];
    const float* embed = (const float*)d_in[1];
    float*       out   = (float*)d_out;

    prep_kernel<<<1024, 256, 0, stream>>>(embed);
    dist_kernel<<<1024, 256, 0, stream>>>(x, embed, out);
}